// Round 17
// baseline (207.954 us; speedup 1.0000x reference)
//
#include <hip/hip_runtime.h>

// Problem constants
#define BB   2
#define SS   2048
#define TT   4096      // B*S
#define HH   32
#define DD   64
#define HIDN 2048      // H*D
#define NQKV 2176      // (H+2)*D
#define QK_SCALE_LOG2 0.1803368801f   // 0.125 * log2(e): scores in log2 domain

#define AS1 __attribute__((address_space(1)))
#define AS3 __attribute__((address_space(3)))

typedef __attribute__((ext_vector_type(8))) short short8;
typedef __attribute__((ext_vector_type(4))) float f32x4;
typedef __attribute__((ext_vector_type(16))) float f32x16;
typedef __attribute__((ext_vector_type(4))) unsigned short ushort4_t;
typedef __attribute__((ext_vector_type(4))) unsigned int uint4_t;

__device__ inline unsigned short f2bf(float f) {
  unsigned int u = __builtin_bit_cast(unsigned int, f);
  u += 0x7FFFu + ((u >> 16) & 1u);   // round-to-nearest-even
  return (unsigned short)(u >> 16);
}
__device__ inline float bf2f(unsigned short s) {
  unsigned int u = ((unsigned int)s) << 16;
  return __builtin_bit_cast(float, u);
}
__device__ inline float exp2fast(float x) { return __builtin_amdgcn_exp2f(x); }

// pack 8 f32 -> 8 bf16 (16B) via v_cvt_pk_bf16_f32
__device__ inline uint4_t pk8(float4 a, float4 b) {
  unsigned int u0, u1, u2, u3;
  asm("v_cvt_pk_bf16_f32 %0, %1, %2" : "=v"(u0) : "v"(a.x), "v"(a.y));
  asm("v_cvt_pk_bf16_f32 %0, %1, %2" : "=v"(u1) : "v"(a.z), "v"(a.w));
  asm("v_cvt_pk_bf16_f32 %0, %1, %2" : "=v"(u2) : "v"(b.x), "v"(b.y));
  asm("v_cvt_pk_bf16_f32 %0, %1, %2" : "=v"(u3) : "v"(b.z), "v"(b.w));
  uint4_t w = { u0, u1, u2, u3 };
  return w;
}

// ----------------------------------------------- QKV GEMM, tail-free 576-grid
// F32-DIRECT operands (no pre-cvt kernel): A = hs f32, B = wqkv f32; staging
// loads 8 f32, converts via v_cvt_pk_bf16_f32, ds_writes 16B to the linear
// LDS slot (source elem index identical to the old pre-swizzled scolu, so the
// swizzled compute loops are unchanged). All staging drained inside the
// two-barrier pair (proven race-free skeleton).
// blocks [0,512): Q-region -> bf16 qout RAW (rope applied on-load in attn).
// blocks [512,576): KV-region split-K=2 -> f32 partials kvp[2][4096][128].
__global__ __launch_bounds__(256)
void gemm_qkv_split(const float* __restrict__ Af, const float* __restrict__ Bf,
                    unsigned short* __restrict__ qout, float* __restrict__ kvp) {
  __shared__ unsigned char lAB[65536];   // A [128][256B] | B [128][256B]
  const int K = HIDN;
  const int tid  = threadIdx.x;
  const int lane = tid & 63;
  const int wv   = tid >> 6;
  const int wr   = wv >> 1, wc = wv & 1;
  const int g    = lane >> 4, qq = lane & 15;

  long bm0, bn0; int kbeg, kend, isQ = 0, ks = 0;
  const int bid = blockIdx.x;
  if (bid < 512) {                     // Q-region, XCD-chunked swizzle
    const int swz = (bid & 7) * 64 + (bid >> 3);
    isQ = 1;
    bm0 = (long)(swz >> 4) * 128;
    bn0 = (long)(swz & 15) * 128;
    kbeg = 0; kend = 2048;
  } else {                             // KV-region split-K
    const int r = bid - 512;           // 0..63
    bm0 = (long)(r >> 1) * 128;
    bn0 = 2048;
    ks  = r & 1;
    kbeg = ks * 1024; kend = kbeg + 1024;
  }

  const int srow = tid >> 4;                                       // 0..15
  const int ecol = 8 * ((tid & 15) ^ (srow & 15));                 // f32 elems

  f32x4 zero = {0.f, 0.f, 0.f, 0.f};
  f32x4 acc[4][4];
#pragma unroll
  for (int m = 0; m < 4; ++m)
#pragma unroll
    for (int n = 0; n < 4; ++n) acc[m][n] = zero;

  const float* aSrc = Af + (bm0 + srow) * (long)K + ecol;
  const float* bSrc = Bf + (bn0 + srow) * (long)K + ecol;
  const int rswz = qq << 4;            // read-row & 15 == qq

  for (int k0 = kbeg; k0 < kend; k0 += 128) {
    __syncthreads();   // previous tile's compute done before overwrite
#pragma unroll
    for (int gg = 0; gg < 8; ++gg) {
      const float* ap = aSrc + k0 + (long)16 * gg * K;
      const float* bp = bSrc + k0 + (long)16 * gg * K;
      float4 a0 = *(const float4*)(ap);
      float4 a1 = *(const float4*)(ap + 4);
      float4 b0 = *(const float4*)(bp);
      float4 b1 = *(const float4*)(bp + 4);
      *(uint4_t*)(lAB + gg * 4096 + (tid << 4))         = pk8(a0, a1);
      *(uint4_t*)(lAB + 32768 + gg * 4096 + (tid << 4)) = pk8(b0, b1);
    }
    __syncthreads();   // drains vmcnt/lgkmcnt -> staged data visible

#pragma unroll
    for (int kss = 0; kss < 4; ++kss) {
      short8 af[4], bf[4];
#pragma unroll
      for (int m = 0; m < 4; ++m)
        af[m] = *(const short8*)(lAB + (wr * 64 + m * 16 + qq) * 256
                                     + ((kss * 64 + g * 16) ^ rswz));
#pragma unroll
      for (int n = 0; n < 4; ++n)
        bf[n] = *(const short8*)(lAB + 32768 + (wc * 64 + n * 16 + qq) * 256
                                     + ((kss * 64 + g * 16) ^ rswz));
#pragma unroll
      for (int m = 0; m < 4; ++m)
#pragma unroll
        for (int n = 0; n < 4; ++n)
          acc[m][n] = __builtin_amdgcn_mfma_f32_16x16x32_bf16(af[m], bf[n], acc[m][n], 0, 0, 0);
    }
  }

  // epilogue: C/D layout col=lane&15, row=(lane>>4)*4+reg
  if (isQ) {
#pragma unroll
    for (int m = 0; m < 4; ++m)
#pragma unroll
      for (int r = 0; r < 4; ++r) {
        long row = bm0 + wr * 64 + m * 16 + g * 4 + r;
#pragma unroll
        for (int n = 0; n < 4; ++n)
          qout[row * 2048 + bn0 + wc * 64 + n * 16 + qq] = f2bf(acc[m][n][r]);
      }
  } else {
    float* dst = kvp + (long)ks * (4096 * 128);
#pragma unroll
    for (int m = 0; m < 4; ++m)
#pragma unroll
      for (int r = 0; r < 4; ++r) {
        long row = bm0 + wr * 64 + m * 16 + g * 4 + r;
#pragma unroll
        for (int n = 0; n < 4; ++n)
          dst[row * 128 + wc * 64 + n * 16 + qq] = acc[m][n][r];
      }
  }
}

// ------------------------------------------------- C = A(MxK) * B(NxK)^T GEMM
// Dense projection: A = attn output (bf16, global_load_lds staging unchanged),
// B = wd F32-DIRECT (reg-staged cvt, same linear-dest scheme). f32 out.
__global__ __launch_bounds__(256)
void gemm_dense(const unsigned short* __restrict__ A, const float* __restrict__ Bf,
                float* __restrict__ Cp, int M, int N, int K) {
  __shared__ unsigned char lAB[65536];
  const int tid  = threadIdx.x;
  const int lane = tid & 63;
  const int wv   = tid >> 6;
  const int wr   = wv >> 1, wc = wv & 1;
  const int g    = lane >> 4, qq = lane & 15;
  const int gx   = gridDim.x;
  const int nwg  = gx * gridDim.y;
  const int lid  = blockIdx.y * gx + blockIdx.x;
  const int swz  = (lid & 7) * (nwg >> 3) + (lid >> 3);
  const long bm0 = (long)(swz / gx) * 128;
  const long bn0 = (long)(swz % gx) * 128;
  const int srow  = tid >> 4;
  const int ecol  = 8 * ((tid & 15) ^ (srow & 15));                // elems
  const int scolu = ecol;                                         // ushorts too

  f32x4 zero = {0.f, 0.f, 0.f, 0.f};
  f32x4 acc[4][4];
#pragma unroll
  for (int m = 0; m < 4; ++m)
#pragma unroll
    for (int n = 0; n < 4; ++n) acc[m][n] = zero;

  const unsigned short* aSrc = A + (bm0 + srow) * (long)K + scolu;
  const float*          bSrc = Bf + (bn0 + srow) * (long)K + ecol;
  const int rswz = qq << 4;

  for (int k0 = 0; k0 < K; k0 += 128) {
    __syncthreads();
#pragma unroll
    for (int gg = 0; gg < 8; ++gg) {
      __builtin_amdgcn_global_load_lds(
          (const AS1 unsigned int*)(aSrc + k0 + (long)16 * gg * K),
          (AS3 unsigned int*)(lAB + gg * 4096 + wv * 1024), 16, 0, 0);
      const float* bp = bSrc + k0 + (long)16 * gg * K;
      float4 b0 = *(const float4*)(bp);
      float4 b1 = *(const float4*)(bp + 4);
      *(uint4_t*)(lAB + 32768 + gg * 4096 + (tid << 4)) = pk8(b0, b1);
    }
    __syncthreads();

#pragma unroll
    for (int kss = 0; kss < 4; ++kss) {
      short8 af[4], bf[4];
#pragma unroll
      for (int m = 0; m < 4; ++m)
        af[m] = *(const short8*)(lAB + (wr * 64 + m * 16 + qq) * 256
                                     + ((kss * 64 + g * 16) ^ rswz));
#pragma unroll
      for (int n = 0; n < 4; ++n)
        bf[n] = *(const short8*)(lAB + 32768 + (wc * 64 + n * 16 + qq) * 256
                                     + ((kss * 64 + g * 16) ^ rswz));
#pragma unroll
      for (int m = 0; m < 4; ++m)
#pragma unroll
        for (int n = 0; n < 4; ++n)
          acc[m][n] = __builtin_amdgcn_mfma_f32_16x16x32_bf16(af[m], bf[n], acc[m][n], 0, 0, 0);
    }
  }

#pragma unroll
  for (int m = 0; m < 4; ++m)
#pragma unroll
    for (int r = 0; r < 4; ++r) {
      long row = bm0 + wr * 64 + m * 16 + g * 4 + r;
#pragma unroll
      for (int n = 0; n < 4; ++n)
        Cp[row * N + bn0 + wc * 64 + n * 16 + qq] = acc[m][n][r];
    }
}

// ----------------------------------------------------------- K/V rope + V^T
// Sums split-K partials kvp[2][4096][128]; ropes k; scatters v into
// tiled-transposed [B][S/64][64 d][64 s]. 32768 threads, 128 blocks.
__global__ __launch_bounds__(256)
void kv_rope_kernel(const float* __restrict__ kvp, const float* __restrict__ cosb,
                    const float* __restrict__ sinb, unsigned short* __restrict__ k_out,
                    unsigned short* __restrict__ v_out) {
  int idx = blockIdx.x * 256 + threadIdx.x;
  if (idx >= TT * 8) return;
  int t   = idx >> 3;
  int rem = idx & 7;
  int i0  = (rem & 3) * 8;
  const float* p0 = kvp + (long)t * 128;
  const float* p1 = kvp + 4096 * 128 + (long)t * 128;

  if ((rem >> 2) == 0) {               // k head (local cols 0..63), rope
    float cv[8], sv[8];
    *(float4*)(cv)     = *(const float4*)(cosb + t * 32 + i0);
    *(float4*)(cv + 4) = *(const float4*)(cosb + t * 32 + i0 + 4);
    *(float4*)(sv)     = *(const float4*)(sinb + t * 32 + i0);
    *(float4*)(sv + 4) = *(const float4*)(sinb + t * 32 + i0 + 4);
    unsigned short* kr2 = k_out + (long)t * 64;
#pragma unroll
    for (int j = 0; j < 8; ++j) {
      float x1 = p0[i0 + j]      + p1[i0 + j];
      float x2 = p0[32 + i0 + j] + p1[32 + i0 + j];
      kr2[i0 + j]      = f2bf(x1 * cv[j] - x2 * sv[j]);
      kr2[32 + i0 + j] = f2bf(x2 * cv[j] + x1 * sv[j]);
    }
  } else {                             // v head (local cols 64..127) -> V^T
    int bb = t >> 11, s = t & 2047;
    int tile = s >> 6, c = s & 63;
    long base = ((long)bb * 32 + tile) * 64;   // row units (64-ushort rows)
#pragma unroll
    for (int j = 0; j < 8; ++j) {
      v_out[(base + i0 + j) * 64 + c]      = f2bf(p0[64 + i0 + j] + p1[64 + i0 + j]);
      v_out[(base + 32 + i0 + j) * 64 + c] = f2bf(p0[96 + i0 + j] + p1[96 + i0 + j]);
    }
  }
}

// -------------------------------------------------------------- flash attention
// Round-16 kernel unchanged (KVBLK=256 two-barrier skeleton + RoPE-on-load Q),
// post-timing validated.
__global__ __launch_bounds__(256, 2)
void attn_kernel(const unsigned short* __restrict__ qs, const unsigned short* __restrict__ kr,
                 const unsigned short* __restrict__ vt, const float* __restrict__ cosb,
                 const float* __restrict__ sinb, unsigned short* __restrict__ ob) {
  __shared__ unsigned char lsm[65536];   // K rows 0-255 (32KB) | V 4 tiles (32KB)
  const int tid  = threadIdx.x;
  const int lane = tid & 63;
  const int wv   = tid >> 6;          // 0..3
  const int half = lane >> 5;
  const int qc   = lane & 31;
  const int h    = blockIdx.y * 4 + wv;
  const int b    = blockIdx.z;
  const int qtA  = blockIdx.x;                   // small triangle
  const int qtB  = (SS / 32 - 1) - blockIdx.x;   // big triangle
  const int q0A  = qtA * 32, q0B = qtB * 32;
  const int nbB  = (q0B >> 8) + 1;               // 256-kv staged blocks

  const unsigned short* kb  = kr + (long)b * SS * 64;
  const unsigned short* vtb = vt + (long)b * (SS / 64) * 64 * 64;

  const int srow = tid >> 3;                                       // 0..31
  const int scol = ((((tid & 7) << 4) ^ ((srow & 7) << 4)) >> 1);  // ushorts

  const int rswz = (qc & 7) << 4;
  int roff[4];
#pragma unroll
  for (int i = 0; i < 4; ++i)
    roff[i] = qc * 128 + ((i * 32 + half * 16) ^ rswz);

  // ---- Q fragments with RoPE-on-load. Lane qc holds q-row t = b*SS+q0+qc;
  // qf[s] covers d = s*16 + half*8 + j (<32), qf[s+2] covers d+32.
  short8 qfA[4], qfB[4];
  {
    const long tA = (long)(b * SS + q0A + qc);
    const long tB = (long)(b * SS + q0B + qc);
    const unsigned short* qrA = qs + (tA * HH + h) * 64;
    const unsigned short* qrB = qs + (tB * HH + h) * 64;
    short8 rA[4], rB[4];
#pragma unroll
    for (int dstep = 0; dstep < 4; ++dstep) {
      rA[dstep] = *(const short8*)(qrA + dstep * 16 + half * 8);
      rB[dstep] = *(const short8*)(qrB + dstep * 16 + half * 8);
    }
    float cvA[16], svA[16], cvB[16], svB[16];
#pragma unroll
    for (int s = 0; s < 2; ++s) {
      const int io = s * 16 + half * 8;
      *(float4*)(cvA + s * 8)     = *(const float4*)(cosb + tA * 32 + io);
      *(float4*)(cvA + s * 8 + 4) = *(const float4*)(cosb + tA * 32 + io + 4);
      *(float4*)(svA + s * 8)     = *(const float4*)(sinb + tA * 32 + io);
      *(float4*)(svA + s * 8 + 4) = *(const float4*)(sinb + tA * 32 + io + 4);
      *(float4*)(cvB + s * 8)     = *(const float4*)(cosb + tB * 32 + io);
      *(float4*)(cvB + s * 8 + 4) = *(const float4*)(cosb + tB * 32 + io + 4);
      *(float4*)(svB + s * 8)     = *(const float4*)(sinb + tB * 32 + io);
      *(float4*)(svB + s * 8 + 4) = *(const float4*)(sinb + tB * 32 + io + 4);
    }
#pragma unroll
    for (int s = 0; s < 2; ++s)
#pragma unroll
      for (int j = 0; j < 8; ++j) {
        float c_ = cvA[s * 8 + j], s_ = svA[s * 8 + j];
        float x1 = bf2f((unsigned short)rA[s][j]);
        float x2 = bf2f((unsigned short)rA[s + 2][j]);
        qfA[s][j]     = (short)f2bf((x1 * c_ - x2 * s_) * QK_SCALE_LOG2);
        qfA[s + 2][j] = (short)f2bf((x2 * c_ + x1 * s_) * QK_SCALE_LOG2);
        c_ = cvB[s * 8 + j]; s_ = svB[s * 8 + j];
        x1 = bf2f((unsigned short)rB[s][j]);
        x2 = bf2f((unsigned short)rB[s + 2][j]);
        qfB[s][j]     = (short)f2bf((x1 * c_ - x2 * s_) * QK_SCALE_LOG2);
        qfB[s + 2][j] = (short)f2bf((x2 * c_ + x1 * s_) * QK_SCALE_LOG2);
      }
  }

  f32x16 oA0, oA1, oB0, oB1;
#pragma unroll
  for (int r = 0; r < 16; ++r) { oA0[r] = 0.f; oA1[r] = 0.f; oB0[r] = 0.f; oB1[r] = 0.f; }
  float mA = -1e30f, lA = 0.f, mB = -1e30f, lB = 0.f;

#define PHASE(qf, o0, o1, mst, lst, q0x, maskNeeded)                             \
  do {                                                                           \
    f32x16 st0, st1;                                                             \
    _Pragma("unroll")                                                            \
    for (int r = 0; r < 16; ++r) { st0[r] = 0.f; st1[r] = 0.f; }                 \
    __builtin_amdgcn_s_setprio(1);                                               \
    _Pragma("unroll")                                                            \
    for (int dstep = 0; dstep < 4; ++dstep) {                                    \
      short8 kfA_ = *(const short8*)(Kb + roff[dstep]);                          \
      short8 kfB_ = *(const short8*)(Kb + roff[dstep] + 4096);                   \
      st0 = __builtin_amdgcn_mfma_f32_32x32x16_bf16(kfA_, qf[dstep], st0, 0, 0, 0); \
      st1 = __builtin_amdgcn_mfma_f32_32x32x16_bf16(kfB_, qf[dstep], st1, 0, 0, 0); \
    }                                                                            \
    __builtin_amdgcn_s_setprio(0);                                               \
    if (maskNeeded) {                                                            \
      _Pragma("unroll")                                                          \
      for (int r = 0; r < 16; ++r) {                                             \
        int rkv = (r & 3) + 8 * (r >> 2) + 4 * half;                             \
        if (kvb + rkv      > (q0x) + qc) st0[r] = -1e30f;                        \
        if (kvb + 32 + rkv > (q0x) + qc) st1[r] = -1e30f;                        \
      }                                                                          \
    }                                                                            \
    float pmax = st0[0];                                                         \
    _Pragma("unroll")                                                            \
    for (int r = 1; r < 16; ++r) pmax = fmaxf(pmax, st0[r]);                     \
    _Pragma("unroll")                                                            \
    for (int r = 0; r < 16; ++r) pmax = fmaxf(pmax, st1[r]);                     \
    pmax = fmaxf(pmax, __shfl_xor(pmax, 32));                                    \
    if (!__all(pmax - mst <= 8.f)) {                                             \
      const float mnew = fmaxf(mst, pmax);                                       \
      const float scal = exp2fast(mst - mnew);                                   \
      lst *= scal;                                                               \
      _Pragma("unroll")                                                          \
      for (int r = 0; r < 16; ++r) { o0[r] *= scal; o1[r] *= scal; }             \
      mst = mnew;                                                                \
    }                                                                            \
    float psum = 0.f;                                                            \
    _Pragma("unroll")                                                            \
    for (int r = 0; r < 16; ++r) { st0[r] = exp2fast(st0[r] - mst); psum += st0[r]; } \
    _Pragma("unroll")                                                            \
    for (int r = 0; r < 16; ++r) { st1[r] = exp2fast(st1[r] - mst); psum += st1[r]; } \
    psum += __shfl_xor(psum, 32);                                                \
    lst += psum;                                                                 \
    short8 pb[4];                                                                \
    _Pragma("unroll")                                                            \
    for (int hseg = 0; hseg < 2; ++hseg) {                                       \
      const f32x16& pp = hseg ? st1 : st0;                                       \
      unsigned int a0, a1, a2, a3, a4, a5, a6, a7;                               \
      asm("v_cvt_pk_bf16_f32 %0, %1, %2" : "=v"(a0) : "v"(pp[0]),  "v"(pp[1]));  \
      asm("v_cvt_pk_bf16_f32 %0, %1, %2" : "=v"(a1) : "v"(pp[2]),  "v"(pp[3]));  \
      asm("v_cvt_pk_bf16_f32 %0, %1, %2" : "=v"(a2) : "v"(pp[4]),  "v"(pp[5]));  \
      asm("v_cvt_pk_bf16_f32 %0, %1, %2" : "=v"(a3) : "v"(pp[6]),  "v"(pp[7]));  \
      asm("v_cvt_pk_bf16_f32 %0, %1, %2" : "=v"(a4) : "v"(pp[8]),  "v"(pp[9]));  \
      asm("v_cvt_pk_bf16_f32 %0, %1, %2" : "=v"(a5) : "v"(pp[10]), "v"(pp[11])); \
      asm("v_cvt_pk_bf16_f32 %0, %1, %2" : "=v"(a6) : "v"(pp[12]), "v"(pp[13])); \
      asm("v_cvt_pk_bf16_f32 %0, %1, %2" : "=v"(a7) : "v"(pp[14]), "v"(pp[15])); \
      asm("v_permlane32_swap_b32 %0, %1" : "+v"(a0), "+v"(a2));                  \
      asm("v_permlane32_swap_b32 %0, %1" : "+v"(a1), "+v"(a3));                  \
      asm("v_permlane32_swap_b32 %0, %1" : "+v"(a4), "+v"(a6));                  \
      asm("v_permlane32_swap_b32 %0, %1" : "+v"(a5), "+v"(a7));                  \
      uint4_t w0 = { a0, a1, a2, a3 };                                           \
      uint4_t w1 = { a4, a5, a6, a7 };                                           \
      pb[hseg * 2]     = __builtin_bit_cast(short8, w0);                         \
      pb[hseg * 2 + 1] = __builtin_bit_cast(short8, w1);                         \
    }                                                                            \
    __builtin_amdgcn_s_setprio(1);                                               \
    _Pragma("unroll")                                                            \
    for (int kss = 0; kss < 4; ++kss) {                                          \
      short8 vfA_ = *(const short8*)(Vb + roff[kss]);                            \
      short8 vfB_ = *(const short8*)(Vb + roff[kss] + 4096);                     \
      o0 = __builtin_amdgcn_mfma_f32_32x32x16_bf16(vfA_, pb[kss], o0, 0, 0, 0);  \
      o1 = __builtin_amdgcn_mfma_f32_32x32x16_bf16(vfB_, pb[kss], o1, 0, 0, 0);  \
    }                                                                            \
    __builtin_amdgcn_s_setprio(0);                                               \
  } while (0)

  for (int ib = 0; ib < nbB; ++ib) {
    const int kv0 = ib * 256;
    __syncthreads();                   // all waves done reading previous tile
    {
      const unsigned short* kS = kb + ((long)(kv0 + srow)) * 64 + scol;
#pragma unroll
      for (int gg = 0; gg < 8; ++gg)
        __builtin_amdgcn_global_load_lds((const AS1 unsigned int*)(kS + gg * 32 * 64),
            (AS3 unsigned int*)(lsm + gg * 4096 + wv * 1024), 16, 0, 0);
      const unsigned short* vS = vtb + (long)(4 * ib) * 4096 + srow * 64 + scol;
#pragma unroll
      for (int gg = 0; gg < 8; ++gg)
        __builtin_amdgcn_global_load_lds((const AS1 unsigned int*)(vS + gg * 32 * 64),
            (AS3 unsigned int*)(lsm + 32768 + gg * 4096 + wv * 1024), 16, 0, 0);
    }
    __syncthreads();                   // drains vmcnt -> staged data visible

    for (int ph = 0; ph < 4; ++ph) {
      const int kvb = kv0 + ph * 64;
      if (kvb > q0B + 31) break;       // nothing left (A range is a subset)
      const unsigned char* Kb = lsm + ph * 8192;
      const unsigned char* Vb = lsm + 32768 + ph * 8192;
      PHASE(qfB, oB0, oB1, mB, lB, q0B, (kvb + 63 > q0B));
      if (kvb <= q0A + 31)
        PHASE(qfA, oA0, oA1, mA, lA, q0A, (kvb + 63 > q0A));
    }
  }
#undef PHASE

  {
    const float inv = 1.f / lA;
    unsigned short* orow = ob + ((long)(b * SS + q0A + qc) * HH + h) * 64;
#pragma unroll
    for (int r = 0; r < 16; ++r) {
      int d0 = (r & 3) + 8 * (r >> 2) + 4 * half;
      orow[d0]      = f2bf(oA0[r] * inv);
      orow[32 + d0] = f2bf(oA1[r] * inv);
    }
  }
  {
    const float inv = 1.f / lB;
    unsigned short* orow = ob + ((long)(b * SS + q0B + qc) * HH + h) * 64;
#pragma unroll
    for (int r = 0; r < 16; ++r) {
      int d0 = (r & 3) + 8 * (r >> 2) + 4 * half;
      orow[d0]      = f2bf(oB0[r] * inv);
      orow[32 + d0] = f2bf(oB1[r] * inv);
    }
  }
}

// ------------------------------------------------------------------- launcher
extern "C" void kernel_launch(void* const* d_in, const int* in_sizes, int n_in,
                              void* d_out, int out_size, void* d_ws, size_t ws_size,
                              hipStream_t stream) {
  const float* hs   = (const float*)d_in[0];
  const float* cosb = (const float*)d_in[1];
  const float* sinb = (const float*)d_in[2];
  const float* wqkv = (const float*)d_in[3];
  const float* wd   = (const float*)d_in[4];

  char* ws = (char*)d_ws;
  unsigned short* q_bf  = (unsigned short*)(ws);                  // 16 MB (raw GEMM out)
  float*          kvp   = (float*)(ws + 16777216);                // 4 MB
  unsigned short* k_bf  = (unsigned short*)(ws + 20971520);       // 0.5 MB
  unsigned short* vt_bf = (unsigned short*)(ws + 21495808);       // 0.5 MB
  unsigned short* aout  = (unsigned short*)(ws + 22020096);       // 16 MB (attn out)

  gemm_qkv_split<<<576, 256, 0, stream>>>(hs, wqkv, q_bf, kvp);

  kv_rope_kernel<<<128, 256, 0, stream>>>(kvp, cosb, sinb, k_bf, vt_bf);

  attn_kernel<<<dim3(SS / 64, 8, BB), 256, 0, stream>>>(q_bf, k_bf, vt_bf,
                                                        cosb, sinb, aout);

  gemm_dense<<<dim3(16, 32), 256, 0, stream>>>(aout, wd, (float*)d_out,
                                               TT, HIDN, HIDN);
}

// Round 18
// 169.062 us; speedup vs baseline: 1.2300x; 1.2300x over previous
//
#include <hip/hip_runtime.h>

// Problem constants
#define BB   2
#define SS   2048
#define TT   4096      // B*S
#define HH   32
#define DD   64
#define HIDN 2048      // H*D
#define NQKV 2176      // (H+2)*D
#define QK_SCALE_LOG2 0.1803368801f   // 0.125 * log2(e): scores in log2 domain

#define AS1 __attribute__((address_space(1)))
#define AS3 __attribute__((address_space(3)))

typedef __attribute__((ext_vector_type(8))) short short8;
typedef __attribute__((ext_vector_type(4))) float f32x4;
typedef __attribute__((ext_vector_type(16))) float f32x16;
typedef __attribute__((ext_vector_type(4))) unsigned short ushort4_t;
typedef __attribute__((ext_vector_type(4))) unsigned int uint4_t;

__device__ inline unsigned short f2bf(float f) {
  unsigned int u = __builtin_bit_cast(unsigned int, f);
  u += 0x7FFFu + ((u >> 16) & 1u);   // round-to-nearest-even
  return (unsigned short)(u >> 16);
}
__device__ inline float bf2f(unsigned short s) {
  unsigned int u = ((unsigned int)s) << 16;
  return __builtin_bit_cast(float, u);
}
__device__ inline float exp2fast(float x) { return __builtin_amdgcn_exp2f(x); }

// --------------------------------------------- f32 -> bf16 (all three inputs)
__global__ __launch_bounds__(256)
void cvt_all_kernel(const float* __restrict__ hs, const float* __restrict__ wqkv,
                    const float* __restrict__ wd, unsigned short* __restrict__ out) {
  int i = blockIdx.x * 256 + threadIdx.x;
  if (i >= 4259840) return;            // total float4 groups
  const float* src; int off;
  if (i < 2097152)      { src = hs;   off = i; }
  else if (i < 3211264) { src = wqkv; off = i - 2097152; }
  else                  { src = wd;   off = i - 3211264; }
  float4 v = ((const float4*)src)[off];
  ushort4_t u = { f2bf(v.x), f2bf(v.y), f2bf(v.z), f2bf(v.w) };
  *(ushort4_t*)(out + (long)i * 4) = u;
}

// ----------------------------------------------- QKV GEMM, tail-free 576-grid
// blocks [0,512): Q-region (N=2048, full K) -> bf16 qout RAW (rope applied
// on-load inside attn). blocks [512,576): KV-region split-K=2 -> f32 partials
// kvp[ks][4096][128]. XCD-balanced. BK=128, [128 rows][256 B] LDS tiles,
// XOR swizzle (row&15)<<4 both-sides. Two-barrier skeleton (proven race-free).
__global__ __launch_bounds__(256)
void gemm_qkv_split(const unsigned short* __restrict__ A, const unsigned short* __restrict__ Bw,
                    unsigned short* __restrict__ qout, float* __restrict__ kvp) {
  __shared__ unsigned char lAB[65536];   // A [128][256B] | B [128][256B]
  const int K = HIDN;
  const int tid  = threadIdx.x;
  const int lane = tid & 63;
  const int wv   = tid >> 6;
  const int wr   = wv >> 1, wc = wv & 1;
  const int g    = lane >> 4, qq = lane & 15;

  long bm0, bn0; int kbeg, kend, isQ = 0, ks = 0;
  const int bid = blockIdx.x;
  if (bid < 512) {                     // Q-region, XCD-chunked swizzle
    const int swz = (bid & 7) * 64 + (bid >> 3);
    isQ = 1;
    bm0 = (long)(swz >> 4) * 128;
    bn0 = (long)(swz & 15) * 128;
    kbeg = 0; kend = 2048;
  } else {                             // KV-region split-K
    const int r = bid - 512;           // 0..63
    bm0 = (long)(r >> 1) * 128;
    bn0 = 2048;
    ks  = r & 1;
    kbeg = ks * 1024; kend = kbeg + 1024;
  }

  const int srow  = tid >> 4;                                        // 0..15
  const int scolu = ((((tid & 15) << 4) ^ ((srow & 15) << 4)) >> 1); // ushorts

  f32x4 zero = {0.f, 0.f, 0.f, 0.f};
  f32x4 acc[4][4];
#pragma unroll
  for (int m = 0; m < 4; ++m)
#pragma unroll
    for (int n = 0; n < 4; ++n) acc[m][n] = zero;

  const unsigned short* aSrc = A  + (bm0 + srow) * K + scolu;
  const unsigned short* bSrc = Bw + (bn0 + srow) * K + scolu;
  const int rswz = qq << 4;            // read-row & 15 == qq

  for (int k0 = kbeg; k0 < kend; k0 += 128) {
    __syncthreads();   // previous tile's compute done before overwrite
#pragma unroll
    for (int gg = 0; gg < 8; ++gg) {
      __builtin_amdgcn_global_load_lds(
          (const AS1 unsigned int*)(aSrc + k0 + (long)16 * gg * K),
          (AS3 unsigned int*)(lAB + gg * 4096 + wv * 1024), 16, 0, 0);
      __builtin_amdgcn_global_load_lds(
          (const AS1 unsigned int*)(bSrc + k0 + (long)16 * gg * K),
          (AS3 unsigned int*)(lAB + 32768 + gg * 4096 + wv * 1024), 16, 0, 0);
    }
    __syncthreads();   // drains vmcnt -> staged data visible

#pragma unroll
    for (int kss = 0; kss < 4; ++kss) {
      short8 af[4], bf[4];
#pragma unroll
      for (int m = 0; m < 4; ++m)
        af[m] = *(const short8*)(lAB + (wr * 64 + m * 16 + qq) * 256
                                     + ((kss * 64 + g * 16) ^ rswz));
#pragma unroll
      for (int n = 0; n < 4; ++n)
        bf[n] = *(const short8*)(lAB + 32768 + (wc * 64 + n * 16 + qq) * 256
                                     + ((kss * 64 + g * 16) ^ rswz));
#pragma unroll
      for (int m = 0; m < 4; ++m)
#pragma unroll
        for (int n = 0; n < 4; ++n)
          acc[m][n] = __builtin_amdgcn_mfma_f32_16x16x32_bf16(af[m], bf[n], acc[m][n], 0, 0, 0);
    }
  }

  // epilogue: C/D layout col=lane&15, row=(lane>>4)*4+reg
  if (isQ) {
#pragma unroll
    for (int m = 0; m < 4; ++m)
#pragma unroll
      for (int r = 0; r < 4; ++r) {
        long row = bm0 + wr * 64 + m * 16 + g * 4 + r;
#pragma unroll
        for (int n = 0; n < 4; ++n)
          qout[row * 2048 + bn0 + wc * 64 + n * 16 + qq] = f2bf(acc[m][n][r]);
      }
  } else {
    float* dst = kvp + (long)ks * (4096 * 128);
#pragma unroll
    for (int m = 0; m < 4; ++m)
#pragma unroll
      for (int r = 0; r < 4; ++r) {
        long row = bm0 + wr * 64 + m * 16 + g * 4 + r;
#pragma unroll
        for (int n = 0; n < 4; ++n)
          dst[row * 128 + wc * 64 + n * 16 + qq] = acc[m][n][r];
      }
  }
}

// ------------------------------------------------- C = A(MxK) * B(NxK)^T GEMM
// Dense projection (f32 out). BK=128, XOR swizzle, XCD block swizzle,
// two-barrier skeleton. Grid 16x32 = 512 blocks.
__global__ __launch_bounds__(256)
void gemm_dense(const unsigned short* __restrict__ A, const unsigned short* __restrict__ Bw,
                float* __restrict__ Cp, int M, int N, int K) {
  __shared__ unsigned char lAB[65536];
  const int tid  = threadIdx.x;
  const int lane = tid & 63;
  const int wv   = tid >> 6;
  const int wr   = wv >> 1, wc = wv & 1;
  const int g    = lane >> 4, qq = lane & 15;
  const int gx   = gridDim.x;
  const int nwg  = gx * gridDim.y;
  const int lid  = blockIdx.y * gx + blockIdx.x;
  const int swz  = (lid & 7) * (nwg >> 3) + (lid >> 3);
  const long bm0 = (long)(swz / gx) * 128;
  const long bn0 = (long)(swz % gx) * 128;
  const int srow  = tid >> 4;
  const int scolu = ((((tid & 15) << 4) ^ ((srow & 15) << 4)) >> 1);

  f32x4 zero = {0.f, 0.f, 0.f, 0.f};
  f32x4 acc[4][4];
#pragma unroll
  for (int m = 0; m < 4; ++m)
#pragma unroll
    for (int n = 0; n < 4; ++n) acc[m][n] = zero;

  const unsigned short* aSrc = A  + (bm0 + srow) * K + scolu;
  const unsigned short* bSrc = Bw + (bn0 + srow) * K + scolu;
  const int rswz = qq << 4;

  for (int k0 = 0; k0 < K; k0 += 128) {
    __syncthreads();
#pragma unroll
    for (int gg = 0; gg < 8; ++gg) {
      __builtin_amdgcn_global_load_lds(
          (const AS1 unsigned int*)(aSrc + k0 + (long)16 * gg * K),
          (AS3 unsigned int*)(lAB + gg * 4096 + wv * 1024), 16, 0, 0);
      __builtin_amdgcn_global_load_lds(
          (const AS1 unsigned int*)(bSrc + k0 + (long)16 * gg * K),
          (AS3 unsigned int*)(lAB + 32768 + gg * 4096 + wv * 1024), 16, 0, 0);
    }
    __syncthreads();

#pragma unroll
    for (int kss = 0; kss < 4; ++kss) {
      short8 af[4], bf[4];
#pragma unroll
      for (int m = 0; m < 4; ++m)
        af[m] = *(const short8*)(lAB + (wr * 64 + m * 16 + qq) * 256
                                     + ((kss * 64 + g * 16) ^ rswz));
#pragma unroll
      for (int n = 0; n < 4; ++n)
        bf[n] = *(const short8*)(lAB + 32768 + (wc * 64 + n * 16 + qq) * 256
                                     + ((kss * 64 + g * 16) ^ rswz));
#pragma unroll
      for (int m = 0; m < 4; ++m)
#pragma unroll
        for (int n = 0; n < 4; ++n)
          acc[m][n] = __builtin_amdgcn_mfma_f32_16x16x32_bf16(af[m], bf[n], acc[m][n], 0, 0, 0);
    }
  }

#pragma unroll
  for (int m = 0; m < 4; ++m)
#pragma unroll
    for (int r = 0; r < 4; ++r) {
      long row = bm0 + wr * 64 + m * 16 + g * 4 + r;
#pragma unroll
      for (int n = 0; n < 4; ++n)
        Cp[row * N + bn0 + wc * 64 + n * 16 + qq] = acc[m][n][r];
    }
}

// ----------------------------------------------------------- K/V rope + V^T
// Sums split-K partials kvp[2][4096][128]; ropes k; scatters v into
// tiled-transposed [B][S/64][64 d][64 s]. 32768 threads, 128 blocks.
__global__ __launch_bounds__(256)
void kv_rope_kernel(const float* __restrict__ kvp, const float* __restrict__ cosb,
                    const float* __restrict__ sinb, unsigned short* __restrict__ k_out,
                    unsigned short* __restrict__ v_out) {
  int idx = blockIdx.x * 256 + threadIdx.x;
  if (idx >= TT * 8) return;
  int t   = idx >> 3;
  int rem = idx & 7;
  int i0  = (rem & 3) * 8;
  const float* p0 = kvp + (long)t * 128;
  const float* p1 = kvp + 4096 * 128 + (long)t * 128;

  if ((rem >> 2) == 0) {               // k head (local cols 0..63), rope
    float cv[8], sv[8];
    *(float4*)(cv)     = *(const float4*)(cosb + t * 32 + i0);
    *(float4*)(cv + 4) = *(const float4*)(cosb + t * 32 + i0 + 4);
    *(float4*)(sv)     = *(const float4*)(sinb + t * 32 + i0);
    *(float4*)(sv + 4) = *(const float4*)(sinb + t * 32 + i0 + 4);
    unsigned short* kr2 = k_out + (long)t * 64;
#pragma unroll
    for (int j = 0; j < 8; ++j) {
      float x1 = p0[i0 + j]      + p1[i0 + j];
      float x2 = p0[32 + i0 + j] + p1[32 + i0 + j];
      kr2[i0 + j]      = f2bf(x1 * cv[j] - x2 * sv[j]);
      kr2[32 + i0 + j] = f2bf(x2 * cv[j] + x1 * sv[j]);
    }
  } else {                             // v head (local cols 64..127) -> V^T
    int bb = t >> 11, s = t & 2047;
    int tile = s >> 6, c = s & 63;
    long base = ((long)bb * 32 + tile) * 64;   // row units (64-ushort rows)
#pragma unroll
    for (int j = 0; j < 8; ++j) {
      v_out[(base + i0 + j) * 64 + c]      = f2bf(p0[64 + i0 + j] + p1[64 + i0 + j]);
      v_out[(base + 32 + i0 + j) * 64 + c] = f2bf(p0[96 + i0 + j] + p1[96 + i0 + j]);
    }
  }
}

// -------------------------------------------------------------- flash attention
// KVBLK=256 two-barrier skeleton + RoPE-on-load Q (round-16, validated).
__global__ __launch_bounds__(256, 2)
void attn_kernel(const unsigned short* __restrict__ qs, const unsigned short* __restrict__ kr,
                 const unsigned short* __restrict__ vt, const float* __restrict__ cosb,
                 const float* __restrict__ sinb, unsigned short* __restrict__ ob) {
  __shared__ unsigned char lsm[65536];   // K rows 0-255 (32KB) | V 4 tiles (32KB)
  const int tid  = threadIdx.x;
  const int lane = tid & 63;
  const int wv   = tid >> 6;          // 0..3
  const int half = lane >> 5;
  const int qc   = lane & 31;
  const int h    = blockIdx.y * 4 + wv;
  const int b    = blockIdx.z;
  const int qtA  = blockIdx.x;                   // small triangle
  const int qtB  = (SS / 32 - 1) - blockIdx.x;   // big triangle
  const int q0A  = qtA * 32, q0B = qtB * 32;
  const int nbB  = (q0B >> 8) + 1;               // 256-kv staged blocks

  const unsigned short* kb  = kr + (long)b * SS * 64;
  const unsigned short* vtb = vt + (long)b * (SS / 64) * 64 * 64;

  const int srow = tid >> 3;                                       // 0..31
  const int scol = ((((tid & 7) << 4) ^ ((srow & 7) << 4)) >> 1);  // ushorts

  const int rswz = (qc & 7) << 4;
  int roff[4];
#pragma unroll
  for (int i = 0; i < 4; ++i)
    roff[i] = qc * 128 + ((i * 32 + half * 16) ^ rswz);

  // ---- Q fragments with RoPE-on-load. Lane qc holds q-row t = b*SS+q0+qc;
  // qf[s] covers d = s*16 + half*8 + j (<32), qf[s+2] covers d+32.
  short8 qfA[4], qfB[4];
  {
    const long tA = (long)(b * SS + q0A + qc);
    const long tB = (long)(b * SS + q0B + qc);
    const unsigned short* qrA = qs + (tA * HH + h) * 64;
    const unsigned short* qrB = qs + (tB * HH + h) * 64;
    short8 rA[4], rB[4];
#pragma unroll
    for (int dstep = 0; dstep < 4; ++dstep) {
      rA[dstep] = *(const short8*)(qrA + dstep * 16 + half * 8);
      rB[dstep] = *(const short8*)(qrB + dstep * 16 + half * 8);
    }
    float cvA[16], svA[16], cvB[16], svB[16];
#pragma unroll
    for (int s = 0; s < 2; ++s) {
      const int io = s * 16 + half * 8;
      *(float4*)(cvA + s * 8)     = *(const float4*)(cosb + tA * 32 + io);
      *(float4*)(cvA + s * 8 + 4) = *(const float4*)(cosb + tA * 32 + io + 4);
      *(float4*)(svA + s * 8)     = *(const float4*)(sinb + tA * 32 + io);
      *(float4*)(svA + s * 8 + 4) = *(const float4*)(sinb + tA * 32 + io + 4);
      *(float4*)(cvB + s * 8)     = *(const float4*)(cosb + tB * 32 + io);
      *(float4*)(cvB + s * 8 + 4) = *(const float4*)(cosb + tB * 32 + io + 4);
      *(float4*)(svB + s * 8)     = *(const float4*)(sinb + tB * 32 + io);
      *(float4*)(svB + s * 8 + 4) = *(const float4*)(sinb + tB * 32 + io + 4);
    }
#pragma unroll
    for (int s = 0; s < 2; ++s)
#pragma unroll
      for (int j = 0; j < 8; ++j) {
        float c_ = cvA[s * 8 + j], s_ = svA[s * 8 + j];
        float x1 = bf2f((unsigned short)rA[s][j]);
        float x2 = bf2f((unsigned short)rA[s + 2][j]);
        qfA[s][j]     = (short)f2bf((x1 * c_ - x2 * s_) * QK_SCALE_LOG2);
        qfA[s + 2][j] = (short)f2bf((x2 * c_ + x1 * s_) * QK_SCALE_LOG2);
        c_ = cvB[s * 8 + j]; s_ = svB[s * 8 + j];
        x1 = bf2f((unsigned short)rB[s][j]);
        x2 = bf2f((unsigned short)rB[s + 2][j]);
        qfB[s][j]     = (short)f2bf((x1 * c_ - x2 * s_) * QK_SCALE_LOG2);
        qfB[s + 2][j] = (short)f2bf((x2 * c_ + x1 * s_) * QK_SCALE_LOG2);
      }
  }

  f32x16 oA0, oA1, oB0, oB1;
#pragma unroll
  for (int r = 0; r < 16; ++r) { oA0[r] = 0.f; oA1[r] = 0.f; oB0[r] = 0.f; oB1[r] = 0.f; }
  float mA = -1e30f, lA = 0.f, mB = -1e30f, lB = 0.f;

#define PHASE(qf, o0, o1, mst, lst, q0x, maskNeeded)                             \
  do {                                                                           \
    f32x16 st0, st1;                                                             \
    _Pragma("unroll")                                                            \
    for (int r = 0; r < 16; ++r) { st0[r] = 0.f; st1[r] = 0.f; }                 \
    __builtin_amdgcn_s_setprio(1);                                               \
    _Pragma("unroll")                                                            \
    for (int dstep = 0; dstep < 4; ++dstep) {                                    \
      short8 kfA_ = *(const short8*)(Kb + roff[dstep]);                          \
      short8 kfB_ = *(const short8*)(Kb + roff[dstep] + 4096);                   \
      st0 = __builtin_amdgcn_mfma_f32_32x32x16_bf16(kfA_, qf[dstep], st0, 0, 0, 0); \
      st1 = __builtin_amdgcn_mfma_f32_32x32x16_bf16(kfB_, qf[dstep], st1, 0, 0, 0); \
    }                                                                            \
    __builtin_amdgcn_s_setprio(0);                                               \
    if (maskNeeded) {                                                            \
      _Pragma("unroll")                                                          \
      for (int r = 0; r < 16; ++r) {                                             \
        int rkv = (r & 3) + 8 * (r >> 2) + 4 * half;                             \
        if (kvb + rkv      > (q0x) + qc) st0[r] = -1e30f;                        \
        if (kvb + 32 + rkv > (q0x) + qc) st1[r] = -1e30f;                        \
      }                                                                          \
    }                                                                            \
    float pmax = st0[0];                                                         \
    _Pragma("unroll")                                                            \
    for (int r = 1; r < 16; ++r) pmax = fmaxf(pmax, st0[r]);                     \
    _Pragma("unroll")                                                            \
    for (int r = 0; r < 16; ++r) pmax = fmaxf(pmax, st1[r]);                     \
    pmax = fmaxf(pmax, __shfl_xor(pmax, 32));                                    \
    if (!__all(pmax - mst <= 8.f)) {                                             \
      const float mnew = fmaxf(mst, pmax);                                       \
      const float scal = exp2fast(mst - mnew);                                   \
      lst *= scal;                                                               \
      _Pragma("unroll")                                                          \
      for (int r = 0; r < 16; ++r) { o0[r] *= scal; o1[r] *= scal; }             \
      mst = mnew;                                                                \
    }                                                                            \
    float psum = 0.f;                                                            \
    _Pragma("unroll")                                                            \
    for (int r = 0; r < 16; ++r) { st0[r] = exp2fast(st0[r] - mst); psum += st0[r]; } \
    _Pragma("unroll")                                                            \
    for (int r = 0; r < 16; ++r) { st1[r] = exp2fast(st1[r] - mst); psum += st1[r]; } \
    psum += __shfl_xor(psum, 32);                                                \
    lst += psum;                                                                 \
    short8 pb[4];                                                                \
    _Pragma("unroll")                                                            \
    for (int hseg = 0; hseg < 2; ++hseg) {                                       \
      const f32x16& pp = hseg ? st1 : st0;                                       \
      unsigned int a0, a1, a2, a3, a4, a5, a6, a7;                               \
      asm("v_cvt_pk_bf16_f32 %0, %1, %2" : "=v"(a0) : "v"(pp[0]),  "v"(pp[1]));  \
      asm("v_cvt_pk_bf16_f32 %0, %1, %2" : "=v"(a1) : "v"(pp[2]),  "v"(pp[3]));  \
      asm("v_cvt_pk_bf16_f32 %0, %1, %2" : "=v"(a2) : "v"(pp[4]),  "v"(pp[5]));  \
      asm("v_cvt_pk_bf16_f32 %0, %1, %2" : "=v"(a3) : "v"(pp[6]),  "v"(pp[7]));  \
      asm("v_cvt_pk_bf16_f32 %0, %1, %2" : "=v"(a4) : "v"(pp[8]),  "v"(pp[9]));  \
      asm("v_cvt_pk_bf16_f32 %0, %1, %2" : "=v"(a5) : "v"(pp[10]), "v"(pp[11])); \
      asm("v_cvt_pk_bf16_f32 %0, %1, %2" : "=v"(a6) : "v"(pp[12]), "v"(pp[13])); \
      asm("v_cvt_pk_bf16_f32 %0, %1, %2" : "=v"(a7) : "v"(pp[14]), "v"(pp[15])); \
      asm("v_permlane32_swap_b32 %0, %1" : "+v"(a0), "+v"(a2));                  \
      asm("v_permlane32_swap_b32 %0, %1" : "+v"(a1), "+v"(a3));                  \
      asm("v_permlane32_swap_b32 %0, %1" : "+v"(a4), "+v"(a6));                  \
      asm("v_permlane32_swap_b32 %0, %1" : "+v"(a5), "+v"(a7));                  \
      uint4_t w0 = { a0, a1, a2, a3 };                                           \
      uint4_t w1 = { a4, a5, a6, a7 };                                           \
      pb[hseg * 2]     = __builtin_bit_cast(short8, w0);                         \
      pb[hseg * 2 + 1] = __builtin_bit_cast(short8, w1);                         \
    }                                                                            \
    __builtin_amdgcn_s_setprio(1);                                               \
    _Pragma("unroll")                                                            \
    for (int kss = 0; kss < 4; ++kss) {                                          \
      short8 vfA_ = *(const short8*)(Vb + roff[kss]);                            \
      short8 vfB_ = *(const short8*)(Vb + roff[kss] + 4096);                     \
      o0 = __builtin_amdgcn_mfma_f32_32x32x16_bf16(vfA_, pb[kss], o0, 0, 0, 0);  \
      o1 = __builtin_amdgcn_mfma_f32_32x32x16_bf16(vfB_, pb[kss], o1, 0, 0, 0);  \
    }                                                                            \
    __builtin_amdgcn_s_setprio(0);                                               \
  } while (0)

  for (int ib = 0; ib < nbB; ++ib) {
    const int kv0 = ib * 256;
    __syncthreads();                   // all waves done reading previous tile
    {
      const unsigned short* kS = kb + ((long)(kv0 + srow)) * 64 + scol;
#pragma unroll
      for (int gg = 0; gg < 8; ++gg)
        __builtin_amdgcn_global_load_lds((const AS1 unsigned int*)(kS + gg * 32 * 64),
            (AS3 unsigned int*)(lsm + gg * 4096 + wv * 1024), 16, 0, 0);
      const unsigned short* vS = vtb + (long)(4 * ib) * 4096 + srow * 64 + scol;
#pragma unroll
      for (int gg = 0; gg < 8; ++gg)
        __builtin_amdgcn_global_load_lds((const AS1 unsigned int*)(vS + gg * 32 * 64),
            (AS3 unsigned int*)(lsm + 32768 + gg * 4096 + wv * 1024), 16, 0, 0);
    }
    __syncthreads();                   // drains vmcnt -> staged data visible

    for (int ph = 0; ph < 4; ++ph) {
      const int kvb = kv0 + ph * 64;
      if (kvb > q0B + 31) break;       // nothing left (A range is a subset)
      const unsigned char* Kb = lsm + ph * 8192;
      const unsigned char* Vb = lsm + 32768 + ph * 8192;
      PHASE(qfB, oB0, oB1, mB, lB, q0B, (kvb + 63 > q0B));
      if (kvb <= q0A + 31)
        PHASE(qfA, oA0, oA1, mA, lA, q0A, (kvb + 63 > q0A));
    }
  }
#undef PHASE

  {
    const float inv = 1.f / lA;
    unsigned short* orow = ob + ((long)(b * SS + q0A + qc) * HH + h) * 64;
#pragma unroll
    for (int r = 0; r < 16; ++r) {
      int d0 = (r & 3) + 8 * (r >> 2) + 4 * half;
      orow[d0]      = f2bf(oA0[r] * inv);
      orow[32 + d0] = f2bf(oA1[r] * inv);
    }
  }
  {
    const float inv = 1.f / lB;
    unsigned short* orow = ob + ((long)(b * SS + q0B + qc) * HH + h) * 64;
#pragma unroll
    for (int r = 0; r < 16; ++r) {
      int d0 = (r & 3) + 8 * (r >> 2) + 4 * half;
      orow[d0]      = f2bf(oB0[r] * inv);
      orow[32 + d0] = f2bf(oB1[r] * inv);
    }
  }
}

// ------------------------------------------------------------------- launcher
extern "C" void kernel_launch(void* const* d_in, const int* in_sizes, int n_in,
                              void* d_out, int out_size, void* d_ws, size_t ws_size,
                              hipStream_t stream) {
  const float* hs   = (const float*)d_in[0];
  const float* cosb = (const float*)d_in[1];
  const float* sinb = (const float*)d_in[2];
  const float* wqkv = (const float*)d_in[3];
  const float* wd   = (const float*)d_in[4];

  char* ws = (char*)d_ws;
  // hs_bf region (16 MB) is reused as the attention-output bf16 buffer:
  // hidden is fully consumed by the QKV GEMM before attn writes it.
  unsigned short* hs_bf   = (unsigned short*)(ws);                 // 16 MB
  unsigned short* wqkv_bf = (unsigned short*)(ws + 16777216);      // 8.9 MB
  unsigned short* wd_bf   = (unsigned short*)(ws + 25690112);      // 8.4 MB
  unsigned short* q_bf    = (unsigned short*)(ws + 34078720);      // 16 MB (raw GEMM out)
  float*          kvp     = (float*)(ws + 50855936);               // 4 MB (2x 4096x128 f32)
  unsigned short* k_bf    = (unsigned short*)(ws + 55050240);      // 0.5 MB
  unsigned short* vt_bf   = (unsigned short*)(ws + 55574528);      // 0.5 MB

  cvt_all_kernel<<<16640, 256, 0, stream>>>(hs, wqkv, wd, hs_bf);

  gemm_qkv_split<<<576, 256, 0, stream>>>(hs_bf, wqkv_bf, q_bf, kvp);

  kv_rope_kernel<<<128, 256, 0, stream>>>(kvp, cosb, sinb, k_bf, vt_bf);

  attn_kernel<<<dim3(SS / 64, 8, BB), 256, 0, stream>>>(q_bf, k_bf, vt_bf,
                                                        cosb, sinb, hs_bf);

  gemm_dense<<<dim3(16, 32), 256, 0, stream>>>(hs_bf, wd_bf, (float*)d_out,
                                               TT, HIDN, HIDN);
}